// Round 2
// baseline (649.585 us; speedup 1.0000x reference)
//
#include <hip/hip_runtime.h>

#define Bq 2
#define Yq 512
#define Xq 512
#define Cq 128
#define CINq 192

typedef __bf16 bf16x8 __attribute__((ext_vector_type(8)));
typedef float f32x4 __attribute__((ext_vector_type(4)));
typedef float f32x16 __attribute__((ext_vector_type(16)));
typedef short s16x8 __attribute__((ext_vector_type(8)));

__device__ __forceinline__ short f2bf_s(float f){
    return __builtin_bit_cast(short, static_cast<__bf16>(f));
}

// ---------------- weight transpose + bf16 convert ----------------
// wT[tap][cout][cin]  <- conv_w[ky][kx][cin][cout]   (9*128*128)
// wpT[cout][cin]      <- W_proj[cin][cout]           (128*192)
__global__ void kprep(const float* __restrict__ conv_w, const float* __restrict__ W_proj,
                      short* __restrict__ wT, short* __restrict__ wpT){
    int tid = blockIdx.x*256 + threadIdx.x;
    if (tid < 9*128*128){
        int tap = tid >> 14; int r = tid & 16383; int co = r >> 7; int ci = r & 127;
        wT[tid] = f2bf_s(conv_w[tap*16384 + ci*128 + co]);
    }
    int e = tid - 9*128*128;
    if (e >= 0 && e < 128*192){
        int co = e / 192; int ci = e - co*192;
        wpT[e] = f2bf_s(W_proj[ci*128 + co]);
    }
}

// ---------------- projection + BN1 + ReLU + scatter ----------------
// (unchanged from round 1 — passed, not the bottleneck this round)
__global__ void __launch_bounds__(256, 2)
kproj(const float* __restrict__ vf, const int* __restrict__ vc,
      const short* __restrict__ wpT, const float* __restrict__ bp,
      const float* __restrict__ g1, const float* __restrict__ be1,
      const float* __restrict__ mu1, const float* __restrict__ va1,
      float* __restrict__ dense, unsigned char* __restrict__ act){
    __shared__ short A[64*200];
    __shared__ int cells[64];
    const int t = threadIdx.x;
    const int v0 = blockIdx.x * 64;

    const float4* vf4 = reinterpret_cast<const float4*>(vf);
    #pragma unroll
    for (int j = 0; j < 12; ++j){
        int i = t + j*256;
        int v = i / 48, kq = i - v*48;
        float4 x = vf4[(size_t)(v0 + v)*48 + kq];
        short4 s; s.x=f2bf_s(x.x); s.y=f2bf_s(x.y); s.z=f2bf_s(x.z); s.w=f2bf_s(x.w);
        *reinterpret_cast<short4*>(&A[v*200 + kq*4]) = s;
    }
    if (t < 64){
        int vi = v0 + t;
        int bi = vc[vi*4 + 0], yi = vc[vi*4 + 2], xi = vc[vi*4 + 3];
        int cell = (bi*Yq + yi)*Xq + xi;
        cells[t] = cell;
        act[cell] = 1;
    }
    __syncthreads();

    const int w  = t >> 6;
    const int l  = t & 63;
    const int lr = l & 15;
    const int q  = l >> 4;

    const short* wp_lane = wpT + (size_t)(w*32 + lr)*192 + q*8;
    bf16x8 bb[2][6];
    #pragma unroll
    for (int n = 0; n < 2; ++n)
        #pragma unroll
        for (int kc = 0; kc < 6; ++kc)
            bb[n][kc] = *reinterpret_cast<const bf16x8*>(wp_lane + n*16*192 + kc*32);

    f32x4 acc[4][2] = {};
    #pragma unroll
    for (int kc = 0; kc < 6; ++kc){
        bf16x8 a[4];
        #pragma unroll
        for (int m = 0; m < 4; ++m)
            a[m] = *reinterpret_cast<const bf16x8*>(&A[(m*16 + lr)*200 + kc*32 + q*8]);
        #pragma unroll
        for (int m = 0; m < 4; ++m)
            #pragma unroll
            for (int n = 0; n < 2; ++n)
                acc[m][n] = __builtin_amdgcn_mfma_f32_16x16x32_bf16(a[m], bb[n][kc], acc[m][n], 0, 0, 0);
    }

    #pragma unroll
    for (int n = 0; n < 2; ++n){
        int c = w*32 + n*16 + lr;
        float s1  = g1[c] * rsqrtf(va1[c] + 1e-5f);
        float sh1 = be1[c] + (bp[c] - mu1[c]) * s1;
        #pragma unroll
        for (int m = 0; m < 4; ++m){
            #pragma unroll
            for (int r = 0; r < 4; ++r){
                int v = m*16 + q*4 + r;
                float val = fmaxf(fmaf(acc[m][n][r], s1, sh1), 0.f);
                atomicAdd(&dense[(size_t)cells[v]*128 + c], val);
            }
        }
    }
}

// ---------------- conv 3x3 + BN2 + ReLU + mask (fused fp32->bf16 stage) ----
// block: 128 x-pos x 128 cout, 4 waves, wave tile 64x64 (m2 x n2), MFMA 32x32x16
// A: row-pipelined LDS dbuf [2][130][128] bf16, XOR-swizzled (c8 ^= x&7)
// B: weights from L2 per-wave registers (prefetch inside unrolled kc loop)
__global__ void __launch_bounds__(256, 2)
kconv(const float* __restrict__ dense, const short* __restrict__ wT,
      const unsigned char* __restrict__ act, const float* __restrict__ cb,
      const float* __restrict__ g2, const float* __restrict__ be2,
      const float* __restrict__ mu2, const float* __restrict__ va2,
      float* __restrict__ out){
    __shared__ short A[2][130*128];
    const int t = threadIdx.x;
    // bijective XCD swizzle: 4096 blocks, 512 per XCD chunk
    const int bid = (blockIdx.x & 7)*512 + (blockIdx.x >> 3);
    const int b   = bid >> 11;
    const int rem = bid & 2047;
    const int y   = rem >> 2;
    const int x0  = (rem & 3) << 7;

    const int w   = t >> 6, l = t & 63;
    const int l31 = l & 31, hi = l >> 5;
    const int wm  = w >> 1, wn = w & 1;

    // ---- stage row (y+ky-1) of fp32 dense -> bf16 LDS buf ----
    #define STAGE(BUF, KY) do {                                               \
        int yy = y + (KY) - 1;                                                \
        const float* srcr = dense + ((size_t)(b*Yq + yy)*Xq)*128;             \
        _Pragma("unroll")                                                     \
        for (int j = 0; j < 9; ++j){                                          \
            int i = t + j*256;                                                \
            if (i < 2080){                                                    \
                int xi = i >> 4, c8 = i & 15;                                 \
                int xx = x0 - 1 + xi;                                         \
                float4 f0 = {0,0,0,0}, f1 = {0,0,0,0};                        \
                if (yy >= 0 && yy < Yq && xx >= 0 && xx < Xq){                \
                    const float4* p = reinterpret_cast<const float4*>(        \
                        srcr + (size_t)xx*128 + c8*8);                        \
                    f0 = p[0]; f1 = p[1];                                     \
                }                                                             \
                s16x8 o;                                                      \
                o[0]=f2bf_s(f0.x); o[1]=f2bf_s(f0.y);                         \
                o[2]=f2bf_s(f0.z); o[3]=f2bf_s(f0.w);                         \
                o[4]=f2bf_s(f1.x); o[5]=f2bf_s(f1.y);                         \
                o[6]=f2bf_s(f1.z); o[7]=f2bf_s(f1.w);                         \
                *reinterpret_cast<s16x8*>(                                    \
                    &A[BUF][xi*128 + ((c8 ^ (xi & 7)) << 3)]) = o;            \
            }                                                                 \
        }                                                                     \
    } while(0)

    f32x16 acc[2][2] = {};
    const short* wt_base = wT + (size_t)(wn*64 + l31)*128 + hi*8;

    STAGE(0, 0);
    __syncthreads();

    #pragma unroll
    for (int ky = 0; ky < 3; ++ky){
        if (ky < 2){ STAGE((ky+1)&1, ky+1); }
        const short* Ab = A[ky&1];
        #pragma unroll
        for (int kx = 0; kx < 3; ++kx){
            const short* wt_tap = wt_base + (ky*3 + kx)*16384;
            const int xin0 = wm*64 + l31 + kx;          // mi=0 row
            const int xin1 = xin0 + 32;                  // mi=1 row
            const int rb0 = xin0*128, k0 = xin0 & 7;
            const int rb1 = xin1*128, k1 = xin1 & 7;
            #pragma unroll
            for (int kc = 0; kc < 8; ++kc){
                bf16x8 b0 = *reinterpret_cast<const bf16x8*>(wt_tap + kc*16);
                bf16x8 b1 = *reinterpret_cast<const bf16x8*>(wt_tap + 4096 + kc*16);
                bf16x8 a0 = *reinterpret_cast<const bf16x8*>(&Ab[rb0 + (((kc*2 + hi) ^ k0) << 3)]);
                bf16x8 a1 = *reinterpret_cast<const bf16x8*>(&Ab[rb1 + (((kc*2 + hi) ^ k1) << 3)]);
                acc[0][0] = __builtin_amdgcn_mfma_f32_32x32x16_bf16(a0, b0, acc[0][0], 0, 0, 0);
                acc[0][1] = __builtin_amdgcn_mfma_f32_32x32x16_bf16(a0, b1, acc[0][1], 0, 0, 0);
                acc[1][0] = __builtin_amdgcn_mfma_f32_32x32x16_bf16(a1, b0, acc[1][0], 0, 0, 0);
                acc[1][1] = __builtin_amdgcn_mfma_f32_32x32x16_bf16(a1, b1, acc[1][1], 0, 0, 0);
            }
        }
        __syncthreads();
    }
    #undef STAGE

    // epilogue: BN2 + ReLU + mask; D layout: col=l31 (cout), row=(r&3)+8*(r>>2)+4*hi
    #pragma unroll
    for (int n = 0; n < 2; ++n){
        int c = wn*64 + n*32 + l31;
        float s2  = g2[c] * rsqrtf(va2[c] + 1e-3f);
        float sh2 = be2[c] + (cb[c] - mu2[c]) * s2;
        #pragma unroll
        for (int mi = 0; mi < 2; ++mi){
            #pragma unroll
            for (int r = 0; r < 16; ++r){
                int pos = wm*64 + mi*32 + (r & 3) + ((r >> 2) << 3) + hi*4;
                size_t cell = (size_t)(b*Yq + y)*Xq + x0 + pos;
                float v = act[cell] ? fmaxf(fmaf(acc[mi][n][r], s2, sh2), 0.f) : 0.f;
                out[cell*128 + c] = v;
            }
        }
    }
}

extern "C" void kernel_launch(void* const* d_in, const int* in_sizes, int n_in,
                              void* d_out, int out_size, void* d_ws, size_t ws_size,
                              hipStream_t stream){
    const float* vf  = (const float*)d_in[0];
    const int*   vc  = (const int*)  d_in[1];
    const float* Wp  = (const float*)d_in[2];
    const float* bp  = (const float*)d_in[3];
    const float* g1  = (const float*)d_in[4];
    const float* be1 = (const float*)d_in[5];
    const float* mu1 = (const float*)d_in[6];
    const float* va1 = (const float*)d_in[7];
    const float* cw  = (const float*)d_in[8];
    const float* cb  = (const float*)d_in[9];
    const float* g2  = (const float*)d_in[10];
    const float* be2 = (const float*)d_in[11];
    const float* mu2 = (const float*)d_in[12];
    const float* va2 = (const float*)d_in[13];
    float* out = (float*)d_out;
    char* ws = (char*)d_ws;

    // ws layout (bytes):
    //   dense fp32 [2][512][512][128] : 268,435,456 @ 0
    //   act  u8    [2][512][512]      :     524,288 @ 268,435,456
    //   wT   bf16  [9][128][128]      :     294,912 @ 268,959,744
    //   wpT  bf16  [128][192]         :      49,152 @ 269,254,656  (end 269,303,808)
    if (ws_size < 269303808ull) return;
    float* dense = (float*)ws;
    unsigned char* act = (unsigned char*)(ws + 268435456);
    short* wT    = (short*)(ws + 268959744);
    short* wpT   = (short*)(ws + 269254656);

    hipMemsetAsync(dense, 0, 268435456, stream);
    hipMemsetAsync(act, 0, 524288, stream);
    kprep<<<672, 256, 0, stream>>>(cw, Wp, wT, wpT);
    kproj<<<6250, 256, 0, stream>>>(vf, vc, wpT, bp, g1, be1, mu1, va1, dense, act);
    kconv<<<4096, 256, 0, stream>>>(dense, wT, act, cb, g2, be2, mu2, va2, out);
}